// Round 4
// baseline (287.981 us; speedup 1.0000x reference)
//
#include <hip/hip_runtime.h>
#include <hip/hip_bf16.h>

typedef __bf16 bf16;
typedef __bf16 bf16x8 __attribute__((ext_vector_type(8)));
typedef __bf16 bf16x4 __attribute__((ext_vector_type(4)));
typedef float f32x4 __attribute__((ext_vector_type(4)));

#define DEVFN static __device__ __forceinline__

DEVFN f32x4 mfma16(bf16x8 a, bf16x8 b, f32x4 c) {
  return __builtin_amdgcn_mfma_f32_16x16x32_bf16(a, b, c, 0, 0, 0);
}

DEVFN float hswish(float x) { return x * fminf(fmaxf(x + 3.f, 0.f), 6.f) * (1.f / 6.f); }
DEVFN float gelu_exact(float x) { return 0.5f * x * (1.f + erff(x * 0.70710678118654752f)); }

DEVFN int tmap(int dir, int b, int g, int m) {
  return dir == 0 ? (b * 4096 + g * 512 + m)
                  : (b * 4096 + (m & 63) * 64 + g * 8 + (m >> 6));
}

// ---------------- convert x: f32 -> bf16 (8 el/thread) ----------------
__global__ __launch_bounds__(256) void convert_x(const float* __restrict__ src,
                                                 bf16* __restrict__ dst) {
  long i = ((long)blockIdx.x * 256 + threadIdx.x) * 8;
  f32x4 a = *(const f32x4*)(src + i);
  f32x4 b = *(const f32x4*)(src + i + 4);
  bf16x8 o;
#pragma unroll
  for (int j = 0; j < 4; j++) { o[j] = (bf16)a[j]; o[4 + j] = (bf16)b[j]; }
  *(bf16x8*)(dst + i) = o;
}

// ---------------- convert all other inputs (f32 -> bf16, table-driven) ----------
// First 7 entries are weights converted WITH transpose: src [K][N] row-major,
// dst[(i%N)*K + i/N] (i.e. [N][K]).
struct ConvArgs { const float* s[24]; bf16* d[24]; };

__global__ __launch_bounds__(256) void convert_w(ConvArgs a) {
  static const int cum[25] = {0, 131072, 196608, 458752, 720896, 723200, 727808, 740608,
                              740864, 741120, 741632, 741888, 742144, 742400, 742656,
                              742912, 742928, 743184, 743200, 743456, 743712, 744736,
                              745248, 745760, 746016};
  static const int Kt[7] = {256, 256, 256, 1024, 256, 512, 512};
  static const int Nt[7] = {512, 256, 1024, 256, 9, 9, 25};
  int g = blockIdx.x * 256 + threadIdx.x;
  if (g >= 746016) return;
  int e = 0;
  while (g >= cum[e + 1]) e++;
  int i = g - cum[e];
  float v = a.s[e][i];
  int di = i;
  if (e < 7) di = (i % Nt[e]) * Kt[e] + i / Nt[e];
  a.d[e][di] = (bf16)v;
}

// ---------------- LayerNorm: one wave per 256-ch row ----------------
__global__ __launch_bounds__(256) void ln_kernel(const bf16* __restrict__ x,
                                                 const bf16* __restrict__ w,
                                                 const bf16* __restrict__ b,
                                                 bf16* __restrict__ out) {
  int tid = threadIdx.x, lane = tid & 63, wv = tid >> 6;
  long row = (long)blockIdx.x * 4 + wv;
  bf16x4 xv = *(const bf16x4*)(x + row * 256 + lane * 4);
  float v[4];
#pragma unroll
  for (int i = 0; i < 4; i++) v[i] = (float)xv[i];
  float s = v[0] + v[1] + v[2] + v[3];
#pragma unroll
  for (int m = 1; m < 64; m <<= 1) s += __shfl_xor(s, m);
  float mu = s * (1.f / 256.f);
  float q = 0.f;
#pragma unroll
  for (int i = 0; i < 4; i++) { float d = v[i] - mu; q += d * d; }
#pragma unroll
  for (int m = 1; m < 64; m <<= 1) q += __shfl_xor(q, m);
  float r = rsqrtf(q * (1.f / 256.f) + 1e-5f);
  bf16x4 wv4 = *(const bf16x4*)(w + lane * 4);
  bf16x4 bv4 = *(const bf16x4*)(b + lane * 4);
  bf16x4 o;
#pragma unroll
  for (int i = 0; i < 4; i++) o[i] = (bf16)((v[i] - mu) * r * (float)wv4[i] + (float)bv4[i]);
  *(bf16x4*)(out + row * 256 + lane * 4) = o;
}

// ---------------- GEMM: C[MxN] = A[MxK] @ BT[NxK]^T + bias (+resid) ----------------
// 128x128 tile, 4 waves (2x2 of 64x64), BK=32, 16x16x32 bf16 MFMA.
// Output: bf16 to C if Cf==null, else f32 to Cf.
__global__ __launch_bounds__(256) void gemm_bt(const bf16* __restrict__ A,
                                               const bf16* __restrict__ BT,
                                               const bf16* __restrict__ bias,
                                               const bf16* __restrict__ resid,
                                               bf16* __restrict__ C,
                                               float* __restrict__ Cf,
                                               int M, int N, int K) {
  __shared__ __align__(16) bf16 Asl[128 * 32];
  __shared__ __align__(16) bf16 Bsl[128 * 32];
  const int tid = threadIdx.x;
  const int lane = tid & 63, wid = tid >> 6;
  const int rowBase = blockIdx.x * 128, colBase = blockIdx.y * 128;
  f32x4 acc[4][4] = {};
  const int e0 = wid * 1024 + lane * 8;
  const int e1 = e0 + 512;
  const int r0 = e0 >> 5, c0 = e0 & 31;
  const int r1 = e1 >> 5, c1 = e1 & 31;
  const bf16* Ab0 = A + (long)(rowBase + r0) * K + c0;
  const bf16* Ab1 = A + (long)(rowBase + r1) * K + c1;
  const bf16* Bb0 = BT + (long)(colBase + r0) * K + c0;
  const bf16* Bb1 = BT + (long)(colBase + r1) * K + c1;
  const int wr = (wid >> 1) * 64, wc = (wid & 1) * 64;
  const int fr = lane & 15, fk = (lane >> 4) * 8;
  for (int k0 = 0; k0 < K; k0 += 32) {
    bf16x8 a0 = *(const bf16x8*)(Ab0 + k0);
    bf16x8 a1 = *(const bf16x8*)(Ab1 + k0);
    bf16x8 b0 = *(const bf16x8*)(Bb0 + k0);
    bf16x8 b1 = *(const bf16x8*)(Bb1 + k0);
    __syncthreads();
    *(bf16x8*)&Asl[e0] = a0;
    *(bf16x8*)&Asl[e1] = a1;
    *(bf16x8*)&Bsl[e0] = b0;
    *(bf16x8*)&Bsl[e1] = b1;
    __syncthreads();
    bf16x8 af[4], bfv[4];
#pragma unroll
    for (int m = 0; m < 4; m++) af[m] = *(const bf16x8*)&Asl[(wr + m * 16 + fr) * 32 + fk];
#pragma unroll
    for (int n = 0; n < 4; n++) bfv[n] = *(const bf16x8*)&Bsl[(wc + n * 16 + fr) * 32 + fk];
#pragma unroll
    for (int m = 0; m < 4; m++)
#pragma unroll
      for (int n = 0; n < 4; n++) acc[m][n] = mfma16(af[m], bfv[n], acc[m][n]);
  }
#pragma unroll
  for (int m = 0; m < 4; m++) {
#pragma unroll
    for (int r = 0; r < 4; r++) {
      int row = rowBase + wr + m * 16 + (lane >> 4) * 4 + r;
#pragma unroll
      for (int n = 0; n < 4; n++) {
        int col = colBase + wc + n * 16 + fr;
        float v = acc[m][n][r] + (float)bias[col];
        if (resid) v += (float)resid[(long)row * N + col];
        if (Cf) Cf[(long)row * N + col] = v;
        else C[(long)row * N + col] = (bf16)v;
      }
    }
  }
}

// ---------------- depthwise 3x3 on hardswish(v), channel-last ----------------
__global__ __launch_bounds__(256) void dwconv_v(const bf16* __restrict__ qv,
                                                const bf16* __restrict__ wt,
                                                const bf16* __restrict__ cb,
                                                bf16* __restrict__ vconv) {
  int tid = threadIdx.x;
  int c0 = (tid & 31) * 8;
  int s = blockIdx.x * 8 + (tid >> 5);
  int h = (s >> 6) & 63, w2 = s & 63;
  long base = (long)(s >> 12) * 4096;
  float acc[8];
#pragma unroll
  for (int j = 0; j < 8; j++) acc[j] = (float)cb[c0 + j];
#pragma unroll
  for (int ky = -1; ky <= 1; ky++) {
    int hy = h + ky;
    if ((unsigned)hy >= 64u) continue;
#pragma unroll
    for (int kx = -1; kx <= 1; kx++) {
      int wx = w2 + kx;
      if ((unsigned)wx >= 64u) continue;
      long t = base + hy * 64 + wx;
      bf16x8 iv = *(const bf16x8*)(qv + t * 512 + 256 + c0);
      bf16x8 wvv = *(const bf16x8*)(wt + ((ky + 1) * 3 + (kx + 1)) * 256 + c0);
#pragma unroll
      for (int j = 0; j < 8; j++) acc[j] += hswish((float)iv[j]) * (float)wvv[j];
    }
  }
  bf16x8 o;
#pragma unroll
  for (int j = 0; j < 8; j++) o[j] = (bf16)acc[j];
  *(bf16x8*)(vconv + (long)s * 256 + c0) = o;
}

// ---------------- cross-window attention ----------------
__global__ __launch_bounds__(256) void attn_kernel(const bf16* __restrict__ qv,
                                                   bf16* __restrict__ aout) {
  __shared__ __align__(16) bf16 Vt[32 * 512];
  __shared__ __align__(16) bf16 Pl[4][16 * 32];
  const int tid = threadIdx.x, lane = tid & 63, wid = tid >> 6;
  const int u = blockIdx.x >> 1, hf = blockIdx.x & 1;
  const int head = u & 3, g = (u >> 2) & 7, dir = (u >> 5) & 1, b = u >> 6;
  const int qch = dir * 128 + head * 32;
  const int vch = 256 + qch;
  for (int i = tid; i < 2048; i += 256) {
    int token = i >> 2, ch = (i & 3) * 8;
    long t = tmap(dir, b, g, token);
    bf16x8 v = *(const bf16x8*)(qv + t * 512 + vch + ch);
#pragma unroll
    for (int j = 0; j < 8; j++) Vt[(ch + j) * 512 + token] = v[j];
  }
  __syncthreads();
  const int fr = lane & 15, fkh = lane >> 4;
  const float scale = 0.17677669529663687f;
  const f32x4 zero = {0.f, 0.f, 0.f, 0.f};
  for (int qt = 0; qt < 4; ++qt) {
    int qrow0 = hf * 256 + wid * 64 + qt * 16;
    long tq = tmap(dir, b, g, qrow0 + fr);
    bf16x8 qf = *(const bf16x8*)(qv + tq * 512 + qch + fkh * 8);
    f32x4 s[32];
#pragma unroll
    for (int kt = 0; kt < 32; kt++) {
      int kv = kt * 16 + fr;
      long tk = tmap(dir, b, g, kv);
      bf16x8 kf = *(const bf16x8*)(qv + tk * 512 + vch + fkh * 8);
      s[kt] = mfma16(qf, kf, zero);
    }
    float mx[4] = {-1e30f, -1e30f, -1e30f, -1e30f};
#pragma unroll
    for (int kt = 0; kt < 32; kt++)
#pragma unroll
      for (int r = 0; r < 4; r++) { s[kt][r] *= scale; mx[r] = fmaxf(mx[r], s[kt][r]); }
#pragma unroll
    for (int r = 0; r < 4; r++) {
      mx[r] = fmaxf(mx[r], __shfl_xor(mx[r], 1));
      mx[r] = fmaxf(mx[r], __shfl_xor(mx[r], 2));
      mx[r] = fmaxf(mx[r], __shfl_xor(mx[r], 4));
      mx[r] = fmaxf(mx[r], __shfl_xor(mx[r], 8));
    }
    float sm[4] = {0.f, 0.f, 0.f, 0.f};
#pragma unroll
    for (int kt = 0; kt < 32; kt++)
#pragma unroll
      for (int r = 0; r < 4; r++) {
        float p = __expf(s[kt][r] - mx[r]);
        s[kt][r] = p;
        sm[r] += p;
      }
#pragma unroll
    for (int r = 0; r < 4; r++) {
      sm[r] += __shfl_xor(sm[r], 1);
      sm[r] += __shfl_xor(sm[r], 2);
      sm[r] += __shfl_xor(sm[r], 4);
      sm[r] += __shfl_xor(sm[r], 8);
    }
    f32x4 o0 = zero, o1 = zero;
    bf16* Pw = &Pl[wid][0];
#pragma unroll
    for (int c = 0; c < 16; c++) {
#pragma unroll
      for (int h2 = 0; h2 < 2; h2++)
#pragma unroll
        for (int r = 0; r < 4; r++)
          Pw[(fkh * 4 + r) * 32 + h2 * 16 + fr] = (bf16)s[2 * c + h2][r];
      bf16x8 pf = *(const bf16x8*)&Pw[fr * 32 + fkh * 8];
      bf16x8 v0 = *(const bf16x8*)&Vt[fr * 512 + c * 32 + fkh * 8];
      bf16x8 v1 = *(const bf16x8*)&Vt[(16 + fr) * 512 + c * 32 + fkh * 8];
      o0 = mfma16(pf, v0, o0);
      o1 = mfma16(pf, v1, o1);
    }
#pragma unroll
    for (int r = 0; r < 4; r++) {
      int row = qrow0 + fkh * 4 + r;
      long to = tmap(dir, b, g, row);
      float inv = 1.f / sm[r];
      aout[to * 256 + qch + fr] = (bf16)(o0[r] * inv);
      aout[to * 256 + qch + 16 + fr] = (bf16)(o1[r] * inv);
    }
  }
}

// ---------------- a = hardswish(attn + vconv) ----------------
__global__ __launch_bounds__(256) void combine_hs(const bf16* __restrict__ a,
                                                  const bf16* __restrict__ vc,
                                                  bf16* __restrict__ out) {
  long i = ((long)blockIdx.x * 256 + threadIdx.x) * 8;
  bf16x8 av = *(const bf16x8*)(a + i);
  bf16x8 vv = *(const bf16x8*)(vc + i);
  bf16x8 o;
#pragma unroll
  for (int j = 0; j < 8; j++) o[j] = (bf16)hswish((float)av[j] + (float)vv[j]);
  *(bf16x8*)(out + i) = o;
}

// ---------------- BN batch stats (deterministic 2-stage) ----------------
__global__ __launch_bounds__(256) void bn_part(const bf16* __restrict__ a2,
                                               float* __restrict__ part) {
  int tid = threadIdx.x, bx = blockIdx.x;
  int c0 = (tid & 31) * 8, rg = tid >> 5;
  float s[8] = {}, q[8] = {};
  for (int i = 0; i < 32; i++) {
    long row = (long)bx * 256 + rg * 32 + i;
    bf16x8 v = *(const bf16x8*)(a2 + row * 256 + c0);
#pragma unroll
    for (int j = 0; j < 8; j++) { float f = (float)v[j]; s[j] += f; q[j] += f * f; }
  }
  long pb = (long)bx * 8 + rg;
#pragma unroll
  for (int j = 0; j < 8; j++) {
    part[pb * 256 + c0 + j] = s[j];
    part[131072 + pb * 256 + c0 + j] = q[j];
  }
}

__global__ void bn_final(const float* __restrict__ part, const bf16* __restrict__ g,
                         const bf16* __restrict__ bb, float* __restrict__ coef) {
  int c = threadIdx.x;
  float s = 0.f, q = 0.f;
  for (int i = 0; i < 512; i++) { s += part[i * 256 + c]; q += part[131072 + i * 256 + c]; }
  float mu = s * (1.f / 16384.f);
  float var = q * (1.f / 16384.f) - mu * mu;
  float sc = (float)g[c] * rsqrtf(var + 1e-5f);
  coef[c] = sc;
  coef[256 + c] = (float)bb[c] - mu * sc;
}

// ---------------- x2 = BN(a2) + DES(res) + res ----------------
__global__ __launch_bounds__(256) void des_combine(const bf16* __restrict__ x,
                                                   const bf16* __restrict__ a2,
                                                   const float* __restrict__ coef,
                                                   const bf16* __restrict__ wr,
                                                   const bf16* __restrict__ br,
                                                   const bf16* __restrict__ wl,
                                                   const bf16* __restrict__ bl,
                                                   bf16* __restrict__ x2) {
  __shared__ float X[4][256], M1[4][256];
  __shared__ float WR[256], WL[256], BR[16], BL[16], SC[256], SH[256];
  int tid = threadIdx.x, lane = tid & 63, wvi = tid >> 6;
  WR[tid] = (float)wr[tid];
  WL[tid] = (float)wl[tid];
  SC[tid] = coef[tid];
  SH[tid] = coef[256 + tid];
  if (tid < 16) { BR[tid] = (float)br[tid]; BL[tid] = (float)bl[tid]; }
  long t = (long)blockIdx.x * 4 + wvi;
  bf16x4 xv = *(const bf16x4*)(x + t * 256 + lane * 4);
#pragma unroll
  for (int i = 0; i < 4; i++) X[wvi][lane * 4 + i] = (float)xv[i];
  __syncthreads();
#pragma unroll
  for (int u2 = 0; u2 < 4; u2++) {
    int e = u2 * 64 + lane, k = e >> 4, p = e & 15;
    float acc = BR[p];
#pragma unroll
    for (int p2 = 0; p2 < 16; p2++) acc += X[wvi][k * 16 + p2] * WR[p2 * 16 + p];
    M1[wvi][e] = gelu_exact(acc);
  }
  __syncthreads();
#pragma unroll
  for (int u2 = 0; u2 < 4; u2++) {
    int e = u2 * 64 + lane, k = e >> 4, p = e & 15;
    float acc = BL[k];
#pragma unroll
    for (int k2 = 0; k2 < 16; k2++) acc += M1[wvi][k2 * 16 + p] * WL[k2 * 16 + k];
    float a2v = (float)a2[t * 256 + e];
    x2[t * 256 + e] = (bf16)(SC[e] * a2v + SH[e] + acc + X[wvi][e]);
  }
}

// ---------------- MixCFN depthwise 3x3 / 5x5 + gelu, channel-last ----------------
__global__ __launch_bounds__(256) void mixconv(const bf16* __restrict__ h1,
                                               const bf16* __restrict__ wt3,
                                               const bf16* __restrict__ b3,
                                               const bf16* __restrict__ wt5,
                                               const bf16* __restrict__ b5,
                                               bf16* __restrict__ hc) {
  int tid = threadIdx.x;
  int cg = tid & 127, c0 = cg * 8;
  int sp = tid >> 7;
  int s0 = blockIdx.x * 8 + sp * 4;
  bool five = (c0 >= 512);
  int cc = five ? (c0 - 512) : c0;
  float acc[4][8];
  {
    const bf16* bp = five ? (b5 + cc) : (b3 + cc);
#pragma unroll
    for (int j = 0; j < 8; j++) {
      float bv = (float)bp[j];
#pragma unroll
      for (int i = 0; i < 4; i++) acc[i][j] = bv;
    }
  }
  if (!five) {
    for (int tap = 0; tap < 9; tap++) {
      int ky = tap / 3 - 1, kx = tap % 3 - 1;
      bf16x8 wvv = *(const bf16x8*)(wt3 + tap * 512 + cc);
#pragma unroll
      for (int i = 0; i < 4; i++) {
        int s = s0 + i;
        int h = (s >> 6) & 63, w2 = s & 63;
        int hy = h + ky, wx = w2 + kx;
        if ((unsigned)hy < 64u && (unsigned)wx < 64u) {
          long t = (long)(s >> 12) * 4096 + hy * 64 + wx;
          bf16x8 iv = *(const bf16x8*)(h1 + t * 1024 + c0);
#pragma unroll
          for (int j = 0; j < 8; j++) acc[i][j] += (float)iv[j] * (float)wvv[j];
        }
      }
    }
  } else {
    for (int tap = 0; tap < 25; tap++) {
      int ky = tap / 5 - 2, kx = tap % 5 - 2;
      bf16x8 wvv = *(const bf16x8*)(wt5 + tap * 512 + cc);
#pragma unroll
      for (int i = 0; i < 4; i++) {
        int s = s0 + i;
        int h = (s >> 6) & 63, w2 = s & 63;
        int hy = h + ky, wx = w2 + kx;
        if ((unsigned)hy < 64u && (unsigned)wx < 64u) {
          long t = (long)(s >> 12) * 4096 + hy * 64 + wx;
          bf16x8 iv = *(const bf16x8*)(h1 + t * 1024 + c0);
#pragma unroll
          for (int j = 0; j < 8; j++) acc[i][j] += (float)iv[j] * (float)wvv[j];
        }
      }
    }
  }
#pragma unroll
  for (int i = 0; i < 4; i++) {
    int s = s0 + i;
    bf16x8 o;
#pragma unroll
    for (int j = 0; j < 8; j++) o[j] = (bf16)gelu_exact(acc[i][j]);
    *(bf16x8*)(hc + (long)s * 1024 + c0) = o;
  }
}

extern "C" void kernel_launch(void* const* d_in, const int* in_sizes, int n_in,
                              void* d_out, int out_size, void* d_ws, size_t ws_size,
                              hipStream_t stream) {
  if (ws_size < 92274688ull) return;

  char* ws = (char*)d_ws;
  float* bncoef = (float*)(ws + 256);   // 512 f32
  // region D: converted bf16 inputs
  char* Dc = ws + 4096;
  auto alloc = [&](size_t bytes) { bf16* p = (bf16*)Dc; Dc += (bytes + 255) & ~(size_t)255; return p; };
  bf16* cx      = alloc(8388608);   // x 16384x256
  bf16* cWqkvT  = alloc(262144);    // [512][256]
  bf16* cWoutT  = alloc(131072);    // [256][256]
  bf16* cfc1T   = alloc(524288);    // [1024][256]
  bf16* cfc2T   = alloc(524288);    // [256][1024]
  bf16* cconvp  = alloc(4608);      // [9][256]
  bf16* cwt3    = alloc(9216);      // [9][512]
  bf16* cwt5    = alloc(25600);     // [25][512]
  bf16* cln1w   = alloc(512);
  bf16* cln1b   = alloc(512);
  bf16* cbqkv   = alloc(1024);
  bf16* cconvpb = alloc(512);
  bf16* cbout   = alloc(512);
  bf16* cbng    = alloc(512);
  bf16* cbnb    = alloc(512);
  bf16* cdwr    = alloc(512);
  bf16* cdbr    = alloc(32);
  bf16* cdwl    = alloc(512);
  bf16* cdbl    = alloc(32);
  bf16* cln2w   = alloc(512);
  bf16* cln2b   = alloc(512);
  bf16* cfc1b   = alloc(2048);
  bf16* cm3b    = alloc(1024);
  bf16* cm5b    = alloc(1024);
  bf16* cfc2b   = alloc(512);
  // region A (32MB @16MB): qv/vconv/attn, later h1
  bf16* qv    = (bf16*)(ws + 16777216);  // 16384x512
  bf16* vconv = (bf16*)(ws + 33554432);  // 16384x256
  bf16* attn  = (bf16*)(ws + 41943040);  // 16384x256
  bf16* h1    = (bf16*)(ws + 16777216);  // 16384x1024 (aliases qv+vconv+attn, dead by then)
  // region B (32MB @48MB): xnb/a2/bnpart, later hc
  bf16* xnb     = (bf16*)(ws + 50331648);  // 16384x256
  bf16* a2      = (bf16*)(ws + 58720256);  // 16384x256
  float* bnpart = (float*)(ws + 67108864); // 2*512*256 f32
  bf16* hc      = (bf16*)(ws + 50331648);  // 16384x1024 (aliases xnb+a2+bnpart)
  // region C: x2 @80MB
  bf16* x2 = (bf16*)(ws + 83886080);       // 16384x256

  convert_x<<<2048, 256, 0, stream>>>((const float*)d_in[0], cx);
  ConvArgs ca;
  const int srcIdx[24] = {5, 9, 19, 25, 7, 21, 23, 3, 4, 6, 8, 10, 11, 12,
                          13, 14, 15, 16, 17, 18, 20, 22, 24, 26};
  bf16* dsts[24] = {cWqkvT, cWoutT, cfc1T, cfc2T, cconvp, cwt3, cwt5, cln1w, cln1b,
                    cbqkv, cconvpb, cbout, cbng, cbnb, cdwr, cdbr, cdwl, cdbl,
                    cln2w, cln2b, cfc1b, cm3b, cm5b, cfc2b};
  for (int i = 0; i < 24; i++) { ca.s[i] = (const float*)d_in[srcIdx[i]]; ca.d[i] = dsts[i]; }
  convert_w<<<2916, 256, 0, stream>>>(ca);

  ln_kernel<<<4096, 256, 0, stream>>>(cx, cln1w, cln1b, xnb);
  gemm_bt<<<dim3(128, 4), 256, 0, stream>>>(xnb, cWqkvT, cbqkv, nullptr, qv, nullptr, 16384, 512, 256);
  dwconv_v<<<2048, 256, 0, stream>>>(qv, cconvp, cconvpb, vconv);
  attn_kernel<<<512, 256, 0, stream>>>(qv, attn);
  combine_hs<<<2048, 256, 0, stream>>>(attn, vconv, attn);
  gemm_bt<<<dim3(128, 2), 256, 0, stream>>>(attn, cWoutT, cbout, nullptr, a2, nullptr, 16384, 256, 256);
  bn_part<<<64, 256, 0, stream>>>(a2, bnpart);
  bn_final<<<1, 256, 0, stream>>>(bnpart, cbng, cbnb, bncoef);
  des_combine<<<4096, 256, 0, stream>>>(cx, a2, bncoef, cdwr, cdbr, cdwl, cdbl, x2);
  ln_kernel<<<4096, 256, 0, stream>>>(x2, cln2w, cln2b, xnb);
  gemm_bt<<<dim3(128, 8), 256, 0, stream>>>(xnb, cfc1T, cfc1b, nullptr, h1, nullptr, 16384, 1024, 256);
  mixconv<<<2048, 256, 0, stream>>>(h1, cwt3, cm3b, cwt5, cm5b, hc);
  // final: f32 output = hc @ fc2 + fc2b + x2
  gemm_bt<<<dim3(128, 2), 256, 0, stream>>>(hc, cfc2T, cfc2b, x2, nullptr, (float*)d_out, 16384, 256, 1024);
}